// Round 7
// baseline (331.510 us; speedup 1.0000x reference)
//
#include <hip/hip_runtime.h>

#define NE 128
#define NI 32
#define NT 160   // NE + NI
#define NC 10
#define BB 512
#define LL 64
#define DD 784
#define KP 800   // K padded to 25*32 for MFMA
#define MM (BB*LL)

// ws layout (float offsets)
#define G_OFF   0
#define G_SZ    (NT*NT)              // 25600
#define WH_OFF  (G_OFF + G_SZ)       // bf16 plane Wh[n][KP], 128000 ushort = 64000 floats
#define WL_OFF  (WH_OFF + 64000)     // bf16 plane Wl[n][KP]
#define U_OFF   (WL_OFF + 64000)     // 153600
#define U_SZ    (MM*NT)              // 5242880

// out layout (float offsets)
#define O_LOGITS 0
#define O_LAST   327680
#define O_RE     332800
#define O_RI     4527104
#define O_BALE   5575680
#define O_BALI   9769984

// LDS-only barrier (recur): publish ds_writes without draining vmcnt.
#define LDS_BARRIER() asm volatile("s_waitcnt lgkmcnt(0)\n\ts_barrier" ::: "memory")

typedef __attribute__((ext_vector_type(8))) short short8;
typedef __attribute__((ext_vector_type(4))) float af4;

static __device__ __forceinline__ unsigned short f2bf(float f) {   // RNE, finite inputs
  unsigned u = __float_as_uint(f);
  return (unsigned short)((u + 0x7FFFu + ((u >> 16) & 1u)) >> 16);
}
static __device__ __forceinline__ float bf2f(unsigned short h) {
  return __uint_as_float((unsigned)h << 16);
}

// Split 8 fp32 into bf16 hi/lo planes using packed HW converts (RNE, same
// rounding as f2bf).
static __device__ __forceinline__ void cvt_split8(const float* f, short8& ah, short8& al) {
  union { short8 s; unsigned u[4]; } H, L;
  #pragma unroll
  for (int p = 0; p < 4; ++p) {
    float lo = f[2*p], hi = f[2*p+1];
    unsigned h;
    asm("v_cvt_pk_bf16_f32 %0, %1, %2" : "=v"(h) : "v"(lo), "v"(hi));
    float rl = lo - __uint_as_float(h << 16);
    float rh = hi - __uint_as_float(h & 0xffff0000u);
    unsigned l;
    asm("v_cvt_pk_bf16_f32 %0, %1, %2" : "=v"(l) : "v"(rl), "v"(rh));
    H.u[p] = h; L.u[p] = l;
  }
  ah = H.s; al = L.s;
}

// ---------------------------------------------------------------------------
// Prep: Dale-rectified recurrent matrix G[k][j] (fp32) + input weights as
// split-bf16 planes Wh/Wl[n][KP] (k-padded with zeros), n-major so a B-frag
// (8 consecutive k of one n) is one 16B load.
// ---------------------------------------------------------------------------
__global__ void prep_kernel(const float* __restrict__ Wxe, const float* __restrict__ Wxi,
                            const float* __restrict__ Wee, const float* __restrict__ Wie,
                            const float* __restrict__ Wei, const float* __restrict__ Wii,
                            float* __restrict__ ws) {
  int idx = blockIdx.x * blockDim.x + threadIdx.x;
  const int total = G_SZ + NT * KP;
  if (idx >= total) return;
  if (idx < G_SZ) {
    int k = idx / NT, j = idx % NT;
    float g;
    if (j < NE) {
      if (k < NE) g =  fmaxf(Wee[j*NE + k], 0.f);
      else        g = -fmaxf(Wie[j*NI + (k-NE)], 0.f);
    } else {
      int ji = j - NE;
      if (k < NE) g =  fmaxf(Wei[ji*NE + k], 0.f);
      else        g = -fmaxf(Wii[ji*NI + (k-NE)], 0.f);
    }
    ws[G_OFF + k*NT + j] = g;
  } else {
    int t = idx - G_SZ;
    int n = t / KP, k = t - n * KP;
    float v = 0.f;
    if (k < DD)
      v = (n < NE) ? fmaxf(Wxe[n*DD + k], 0.f) : fmaxf(Wxi[(n-NE)*DD + k], 0.f);
    unsigned short h = f2bf(v);
    unsigned short l = f2bf(v - bf2f(h));
    ((unsigned short*)(ws + WH_OFF))[t] = h;
    ((unsigned short*)(ws + WL_OFF))[t] = l;
  }
}

// ---------------------------------------------------------------------------
// GEMM v7 (unchanged this round): 2-phase LDS double-buffered MFMA GEMM.
// ---------------------------------------------------------------------------
static __device__ __forceinline__ void stage_tile(const unsigned short* __restrict__ Wh,
                                                  const unsigned short* __restrict__ Wl,
                                                  unsigned short* dstBase, int kb, int tid) {
  #pragma unroll
  for (int i = 0; i < 5; ++i) {
    const int idx = i * 256 + tid;
    const int row = idx >> 3;
    const int phys = idx & 7;
    const int logical = phys ^ (row & 7);
    const unsigned short* src =
        ((logical & 4) ? Wl : Wh) + (size_t)row * KP + kb + (logical & 3) * 8;
    __builtin_amdgcn_global_load_lds(
        (const __attribute__((address_space(1))) unsigned int*)src,
        (__attribute__((address_space(3))) unsigned int*)(dstBase + idx * 8),
        16, 0, 0);
  }
}

__global__ __launch_bounds__(256, 1) void gemm_kernel(const float* __restrict__ X,
                                                      const float* __restrict__ ws,
                                                      float* __restrict__ U) {
  __shared__ unsigned short tile[2][10240];   // 2 x 20480 B

  const int tid  = threadIdx.x;
  const int lane = tid & 63;
  const int wave = tid >> 6;
  const int n16  = lane & 15;
  const int quad = lane >> 4;
  const int sw   = n16 & 7;
  const int mbase = blockIdx.x * 128 + wave * 32;

  const unsigned short* Wh = (const unsigned short*)(ws + WH_OFF);
  const unsigned short* Wl = (const unsigned short*)(ws + WL_OFF);

  af4 acc[2][10];
  #pragma unroll
  for (int ms = 0; ms < 2; ++ms)
    #pragma unroll
    for (int nt = 0; nt < 10; ++nt)
      #pragma unroll
      for (int r = 0; r < 4; ++r) acc[ms][nt][r] = 0.f;

  const float* xr0 = X + (size_t)(mbase + n16) * DD;
  const float* xr1 = xr0 + (size_t)16 * DD;

  // ---- prologue: stage B-tile for ks=0, load A for ks=0 ----
  stage_tile(Wh, Wl, tile[0], 0, tid);
  float fa0[8], fa1[8];
  {
    const int kb = quad * 8;
    float4 v0 = *(const float4*)(xr0 + kb);
    float4 v1 = *(const float4*)(xr0 + kb + 4);
    fa0[0]=v0.x; fa0[1]=v0.y; fa0[2]=v0.z; fa0[3]=v0.w;
    fa0[4]=v1.x; fa0[5]=v1.y; fa0[6]=v1.z; fa0[7]=v1.w;
    float4 w0 = *(const float4*)(xr1 + kb);
    float4 w1 = *(const float4*)(xr1 + kb + 4);
    fa1[0]=w0.x; fa1[1]=w0.y; fa1[2]=w0.z; fa1[3]=w0.w;
    fa1[4]=w1.x; fa1[5]=w1.y; fa1[6]=w1.z; fa1[7]=w1.w;
  }
  __syncthreads();   // drains vmcnt: buf0 staged, A ready

  // ---- main loop: 25 k-steps ----
  for (int ks = 0; ks < 25; ++ks) {
    const int cur = ks & 1;
    if (ks < 24) stage_tile(Wh, Wl, tile[cur ^ 1], (ks + 1) * 32, tid);

    // A prefetch for ks+1 (masked past DD; zeros harmless, B zero-padded)
    float nf0[8] = {0,0,0,0,0,0,0,0};
    float nf1[8] = {0,0,0,0,0,0,0,0};
    {
      const int nkb = (ks + 1) * 32 + quad * 8;
      if (nkb < DD) {
        float4 v0 = *(const float4*)(xr0 + nkb);
        float4 v1 = *(const float4*)(xr0 + nkb + 4);
        nf0[0]=v0.x; nf0[1]=v0.y; nf0[2]=v0.z; nf0[3]=v0.w;
        nf0[4]=v1.x; nf0[5]=v1.y; nf0[6]=v1.z; nf0[7]=v1.w;
        float4 w0 = *(const float4*)(xr1 + nkb);
        float4 w1 = *(const float4*)(xr1 + nkb + 4);
        nf1[0]=w0.x; nf1[1]=w0.y; nf1[2]=w0.z; nf1[3]=w0.w;
        nf1[4]=w1.x; nf1[5]=w1.y; nf1[6]=w1.z; nf1[7]=w1.w;
      }
    }

    // B frags from LDS (swizzled slots)
    short8 bh[10], bl[10];
    const unsigned short* tb = tile[cur];
    #pragma unroll
    for (int nt = 0; nt < 10; ++nt) {
      const int ro = (nt * 16 + n16) * 64;              // ushort units (128 B/row)
      bh[nt] = *(const short8*)(tb + ro + ((quad ^ sw) << 3));
      bl[nt] = *(const short8*)(tb + ro + (((4 | quad) ^ sw) << 3));
    }

    short8 ah0, al0, ah1, al1;
    cvt_split8(fa0, ah0, al0);
    cvt_split8(fa1, ah1, al1);

    #pragma unroll
    for (int nt = 0; nt < 10; ++nt) {
      acc[0][nt] = __builtin_amdgcn_mfma_f32_16x16x32_bf16(ah0, bh[nt], acc[0][nt], 0, 0, 0);
      acc[1][nt] = __builtin_amdgcn_mfma_f32_16x16x32_bf16(ah1, bh[nt], acc[1][nt], 0, 0, 0);
      acc[0][nt] = __builtin_amdgcn_mfma_f32_16x16x32_bf16(ah0, bl[nt], acc[0][nt], 0, 0, 0);
      acc[1][nt] = __builtin_amdgcn_mfma_f32_16x16x32_bf16(ah1, bl[nt], acc[1][nt], 0, 0, 0);
      acc[0][nt] = __builtin_amdgcn_mfma_f32_16x16x32_bf16(al0, bh[nt], acc[0][nt], 0, 0, 0);
      acc[1][nt] = __builtin_amdgcn_mfma_f32_16x16x32_bf16(al1, bh[nt], acc[1][nt], 0, 0, 0);
    }

    #pragma unroll
    for (int j = 0; j < 8; ++j) { fa0[j] = nf0[j]; fa1[j] = nf1[j]; }

    __syncthreads();   // next buffer fully staged (all waves), reads done
  }

  // ---- epilogue: D row = quad*4 + reg, col = n16 ----
  #pragma unroll
  for (int ms = 0; ms < 2; ++ms)
    #pragma unroll
    for (int nt = 0; nt < 10; ++nt)
      #pragma unroll
      for (int r = 0; r < 4; ++r) {
        const int row = mbase + ms * 16 + quad * 4 + r;
        U[(size_t)row * NT + nt * 16 + n16] = acc[ms][nt][r];
      }
}

// ---------------------------------------------------------------------------
// Recurrent scan v5. Post-mortem of v3/v4: ws is const+restrict, so LLVM
// treats the pre-loop G loads as REMATERIALIZABLE and legally re-loads all
// g[][] from L1 every time step (sunk past the asm memory clobber); its cost
// model prefers ~50-100 VMEM issues/thread/step over 50-100 live VGPRs
// (VGPR_Count 84/52 both below the array footprint). Fix: pin each g value
// with asm volatile("" : "+v") after the pre-loop load — the value becomes
// opaque, cannot be re-derived from memory, and must stay in a VGPR.
// Partition (as v4): 512 thr, kc=lane>>2 (16 x 10 k), jc=wave*4+(lane&3)
// (32 x 5 j), g[10][5]=50 VGPR + ~35 state fits the 128 cap of (512,4).
// Butterfly reduce over lane bits 2..5.
// ---------------------------------------------------------------------------
__global__ __launch_bounds__(512, 4) void recur_kernel(
    const float* __restrict__ ws,
    const float* __restrict__ be, const float* __restrict__ bi,
    float* __restrict__ out) {
  __shared__ float rbuf[2][NT];       // [parity][j]
  __shared__ float balbuf[2][NT];
  __shared__ float biasL[NT];

  const int tid  = threadIdx.x;
  const int lane = tid & 63;
  const int wave = tid >> 6;                  // 0..7
  const int jc   = (wave << 2) | (lane & 3);  // 0..31
  const int kc   = lane >> 2;                 // 0..15
  const int j0   = jc * 5;
  const int k0   = kc * 10;
  const int b    = blockIdx.x;

  const float* G = ws + G_OFF;
  const float* U = ws + U_OFF;

  float g[10][5];
  #pragma unroll
  for (int kk = 0; kk < 10; ++kk)
    #pragma unroll
    for (int c = 0; c < 5; ++c) {
      g[kk][c] = G[(size_t)(k0 + kk) * NT + j0 + c];
      asm volatile("" : "+v"(g[kk][c]));   // pin: not rematerializable
    }

  if (tid < NT) biasL[tid] = (tid < NE) ? be[tid] : bi[tid - NE];
  for (int i = tid; i < 2 * NT; i += 512) (&rbuf[0][0])[i] = 0.f;

  const bool owner = (kc == 0);
  float u[5];
  if (owner) {
    const size_t ub = ((size_t)b * LL) * NT + j0;
    #pragma unroll
    for (int c = 0; c < 5; ++c) u[c] = U[ub + c];
  }
  float s[5];
  #pragma unroll
  for (int c = 0; c < 5; ++c) s[c] = 0.f;

  __syncthreads();

  for (int l = 0; l < LL; ++l) {
    const int p = l & 1;
    // ---- store step l-1 outputs (no barrier depends on these) ----
    if (l > 0) {
      const size_t ob = (size_t)b * LL + (l - 1);
      if (tid < NE) {
        out[O_RE   + ob * NE + tid] = rbuf[p][tid];
        out[O_BALE + ob * NE + tid] = balbuf[p][tid];
      } else if (tid < NT) {
        const int j2 = tid - NE;
        out[O_RI   + ob * NI + j2] = rbuf[p][NE + j2];
        out[O_BALI + ob * NI + j2] = balbuf[p][NE + j2];
      }
    }
    // ---- prefetch next step's U (owners) ----
    float nu[5];
    if (owner && l + 1 < LL) {
      const size_t nb = ((size_t)b * LL + (l + 1)) * NT + j0;
      #pragma unroll
      for (int c = 0; c < 5; ++c) nu[c] = U[nb + c];
    }
    // ---- partial dots over this thread's 10-k chunk ----
    float a[5];
    #pragma unroll
    for (int c = 0; c < 5; ++c) a[c] = 0.f;
    #pragma unroll
    for (int kk2 = 0; kk2 < 5; ++kk2) {
      float2 rv = *(const float2*)(&rbuf[p][k0 + kk2 * 2]);
      #pragma unroll
      for (int c = 0; c < 5; ++c)
        a[c] += rv.x * g[kk2*2+0][c] + rv.y * g[kk2*2+1][c];
    }
    // ---- butterfly reduce over kc (lane bits 2..5) ----
    #pragma unroll
    for (int c = 0; c < 5; ++c) {
      float v = a[c];
      v += __shfl_xor(v, 4, 64);
      v += __shfl_xor(v, 8, 64);
      v += __shfl_xor(v, 16, 64);
      v += __shfl_xor(v, 32, 64);
      a[c] = v;
    }
    // ---- owner lanes update state, write next-parity buffers ----
    if (owner) {
      #pragma unroll
      for (int c = 0; c < 5; ++c) {
        float bal = a[c] + u[c];
        balbuf[1 - p][j0 + c] = bal;
        float sn = 0.5f * (s[c] + bal + biasL[j0 + c]);
        s[c] = sn;
        rbuf[1 - p][j0 + c] = fmaxf(sn, 0.f);
      }
      #pragma unroll
      for (int c = 0; c < 5; ++c) u[c] = nu[c];
    }
    LDS_BARRIER();
  }
  // ---- final store: step 63 outputs live in parity-0 buffers ----
  {
    const size_t ob = (size_t)b * LL + 63;
    if (tid < NE) {
      out[O_RE   + ob * NE + tid] = rbuf[0][tid];
      out[O_BALE + ob * NE + tid] = balbuf[0][tid];
    } else if (tid < NT) {
      const int j2 = tid - NE;
      out[O_RI   + ob * NI + j2] = rbuf[0][NE + j2];
      out[O_BALI + ob * NI + j2] = balbuf[0][NE + j2];
    }
  }
}

// ---------------------------------------------------------------------------
// Logits: [32768 x 128] @ Wro^T + bro. One thread per (m, class).
// ---------------------------------------------------------------------------
__global__ __launch_bounds__(256) void logits_kernel(const float* __restrict__ Wro,
                                                     const float* __restrict__ bro,
                                                     float* __restrict__ out) {
  __shared__ float WroL[NC * 132];   // row-stride 132 breaks bank alignment
  __shared__ float broL[NC];
  const int tid = threadIdx.x;
  for (int i = tid; i < NC * NE; i += 256) {
    int c = i >> 7, k = i & 127;
    WroL[c * 132 + k] = Wro[i];
  }
  if (tid < NC) broL[tid] = bro[tid];
  __syncthreads();
  const int idx = blockIdx.x * 256 + tid;   // 0..327679 exact
  const int m = idx / 10, c = idx - m * 10;
  const float* re = out + O_RE + (size_t)m * NE;
  float v = broL[c];
  #pragma unroll
  for (int t4 = 0; t4 < 32; ++t4) {
    float4 rv = *(const float4*)(re + t4 * 4);
    float4 wv = *(const float4*)(&WroL[c * 132 + t4 * 4]);
    v += rv.x * wv.x + rv.y * wv.y + rv.z * wv.z + rv.w * wv.w;
  }
  out[O_LOGITS + (size_t)m * NC + c] = v;
  if ((m & 63) == 63) out[O_LAST + (size_t)(m >> 6) * NC + c] = v;
}

extern "C" void kernel_launch(void* const* d_in, const int* in_sizes, int n_in,
                              void* d_out, int out_size, void* d_ws, size_t ws_size,
                              hipStream_t stream) {
  const float* x   = (const float*)d_in[0];
  const float* Wxe = (const float*)d_in[1];
  const float* Wxi = (const float*)d_in[2];
  const float* Wee = (const float*)d_in[3];
  const float* Wie = (const float*)d_in[4];
  const float* Wei = (const float*)d_in[5];
  const float* Wii = (const float*)d_in[6];
  const float* be  = (const float*)d_in[7];
  const float* bi  = (const float*)d_in[8];
  const float* Wro = (const float*)d_in[9];
  const float* bro = (const float*)d_in[10];
  float* ws  = (float*)d_ws;
  float* out = (float*)d_out;

  hipLaunchKernelGGL(prep_kernel, dim3((G_SZ + NT*KP + 255)/256), dim3(256), 0, stream,
                     Wxe, Wxi, Wee, Wie, Wei, Wii, ws);
  hipLaunchKernelGGL(gemm_kernel, dim3(MM/128), dim3(256), 0, stream,
                     x, ws, ws + U_OFF);
  hipLaunchKernelGGL(recur_kernel, dim3(BB), dim3(512), 0, stream,
                     ws, be, bi, out);
  hipLaunchKernelGGL(logits_kernel, dim3(MM * NC / 256), dim3(256), 0, stream,
                     Wro, bro, out);
}

// Round 8
// 275.435 us; speedup vs baseline: 1.2036x; 1.2036x over previous
//
#include <hip/hip_runtime.h>

#define NE 128
#define NI 32
#define NT 160   // NE + NI
#define NC 10
#define BB 512
#define LL 64
#define DD 784
#define KP 800   // K padded to 25*32 for MFMA
#define MM (BB*LL)

// ws layout (float offsets)
#define G_OFF   0
#define G_SZ    (NT*NT)              // 25600
#define WH_OFF  (G_OFF + G_SZ)       // bf16 plane Wh[n][KP], 128000 ushort = 64000 floats
#define WL_OFF  (WH_OFF + 64000)     // bf16 plane Wl[n][KP]
#define U_OFF   (WL_OFF + 64000)     // 153600
#define U_SZ    (MM*NT)              // 5242880

// out layout (float offsets)
#define O_LOGITS 0
#define O_LAST   327680
#define O_RE     332800
#define O_RI     4527104
#define O_BALE   5575680
#define O_BALI   9769984

// LDS-only barrier (recur): publish ds_writes without draining vmcnt.
#define LDS_BARRIER() asm volatile("s_waitcnt lgkmcnt(0)\n\ts_barrier" ::: "memory")

typedef __attribute__((ext_vector_type(8))) short short8;
typedef __attribute__((ext_vector_type(4))) float af4;

static __device__ __forceinline__ unsigned short f2bf(float f) {   // RNE, finite inputs
  unsigned u = __float_as_uint(f);
  return (unsigned short)((u + 0x7FFFu + ((u >> 16) & 1u)) >> 16);
}
static __device__ __forceinline__ float bf2f(unsigned short h) {
  return __uint_as_float((unsigned)h << 16);
}

// Split 8 fp32 into bf16 hi/lo planes using packed HW converts (RNE, same
// rounding as f2bf).
static __device__ __forceinline__ void cvt_split8(const float* f, short8& ah, short8& al) {
  union { short8 s; unsigned u[4]; } H, L;
  #pragma unroll
  for (int p = 0; p < 4; ++p) {
    float lo = f[2*p], hi = f[2*p+1];
    unsigned h;
    asm("v_cvt_pk_bf16_f32 %0, %1, %2" : "=v"(h) : "v"(lo), "v"(hi));
    float rl = lo - __uint_as_float(h << 16);
    float rh = hi - __uint_as_float(h & 0xffff0000u);
    unsigned l;
    asm("v_cvt_pk_bf16_f32 %0, %1, %2" : "=v"(l) : "v"(rl), "v"(rh));
    H.u[p] = h; L.u[p] = l;
  }
  ah = H.s; al = L.s;
}

// ---------------------------------------------------------------------------
// Prep: Dale-rectified recurrent matrix G[k][j] (fp32) + input weights as
// split-bf16 planes Wh/Wl[n][KP] (k-padded with zeros), n-major so a B-frag
// (8 consecutive k of one n) is one 16B load.
// ---------------------------------------------------------------------------
__global__ void prep_kernel(const float* __restrict__ Wxe, const float* __restrict__ Wxi,
                            const float* __restrict__ Wee, const float* __restrict__ Wie,
                            const float* __restrict__ Wei, const float* __restrict__ Wii,
                            float* __restrict__ ws) {
  int idx = blockIdx.x * blockDim.x + threadIdx.x;
  const int total = G_SZ + NT * KP;
  if (idx >= total) return;
  if (idx < G_SZ) {
    int k = idx / NT, j = idx % NT;
    float g;
    if (j < NE) {
      if (k < NE) g =  fmaxf(Wee[j*NE + k], 0.f);
      else        g = -fmaxf(Wie[j*NI + (k-NE)], 0.f);
    } else {
      int ji = j - NE;
      if (k < NE) g =  fmaxf(Wei[ji*NE + k], 0.f);
      else        g = -fmaxf(Wii[ji*NI + (k-NE)], 0.f);
    }
    ws[G_OFF + k*NT + j] = g;
  } else {
    int t = idx - G_SZ;
    int n = t / KP, k = t - n * KP;
    float v = 0.f;
    if (k < DD)
      v = (n < NE) ? fmaxf(Wxe[n*DD + k], 0.f) : fmaxf(Wxi[(n-NE)*DD + k], 0.f);
    unsigned short h = f2bf(v);
    unsigned short l = f2bf(v - bf2f(h));
    ((unsigned short*)(ws + WH_OFF))[t] = h;
    ((unsigned short*)(ws + WL_OFF))[t] = l;
  }
}

// ---------------------------------------------------------------------------
// GEMM v7 (unchanged, ~58 us): 2-phase LDS double-buffered MFMA GEMM.
// ---------------------------------------------------------------------------
static __device__ __forceinline__ void stage_tile(const unsigned short* __restrict__ Wh,
                                                  const unsigned short* __restrict__ Wl,
                                                  unsigned short* dstBase, int kb, int tid) {
  #pragma unroll
  for (int i = 0; i < 5; ++i) {
    const int idx = i * 256 + tid;
    const int row = idx >> 3;
    const int phys = idx & 7;
    const int logical = phys ^ (row & 7);
    const unsigned short* src =
        ((logical & 4) ? Wl : Wh) + (size_t)row * KP + kb + (logical & 3) * 8;
    __builtin_amdgcn_global_load_lds(
        (const __attribute__((address_space(1))) unsigned int*)src,
        (__attribute__((address_space(3))) unsigned int*)(dstBase + idx * 8),
        16, 0, 0);
  }
}

__global__ __launch_bounds__(256, 1) void gemm_kernel(const float* __restrict__ X,
                                                      const float* __restrict__ ws,
                                                      float* __restrict__ U) {
  __shared__ unsigned short tile[2][10240];   // 2 x 20480 B

  const int tid  = threadIdx.x;
  const int lane = tid & 63;
  const int wave = tid >> 6;
  const int n16  = lane & 15;
  const int quad = lane >> 4;
  const int sw   = n16 & 7;
  const int mbase = blockIdx.x * 128 + wave * 32;

  const unsigned short* Wh = (const unsigned short*)(ws + WH_OFF);
  const unsigned short* Wl = (const unsigned short*)(ws + WL_OFF);

  af4 acc[2][10];
  #pragma unroll
  for (int ms = 0; ms < 2; ++ms)
    #pragma unroll
    for (int nt = 0; nt < 10; ++nt)
      #pragma unroll
      for (int r = 0; r < 4; ++r) acc[ms][nt][r] = 0.f;

  const float* xr0 = X + (size_t)(mbase + n16) * DD;
  const float* xr1 = xr0 + (size_t)16 * DD;

  // ---- prologue: stage B-tile for ks=0, load A for ks=0 ----
  stage_tile(Wh, Wl, tile[0], 0, tid);
  float fa0[8], fa1[8];
  {
    const int kb = quad * 8;
    float4 v0 = *(const float4*)(xr0 + kb);
    float4 v1 = *(const float4*)(xr0 + kb + 4);
    fa0[0]=v0.x; fa0[1]=v0.y; fa0[2]=v0.z; fa0[3]=v0.w;
    fa0[4]=v1.x; fa0[5]=v1.y; fa0[6]=v1.z; fa0[7]=v1.w;
    float4 w0 = *(const float4*)(xr1 + kb);
    float4 w1 = *(const float4*)(xr1 + kb + 4);
    fa1[0]=w0.x; fa1[1]=w0.y; fa1[2]=w0.z; fa1[3]=w0.w;
    fa1[4]=w1.x; fa1[5]=w1.y; fa1[6]=w1.z; fa1[7]=w1.w;
  }
  __syncthreads();   // drains vmcnt: buf0 staged, A ready

  // ---- main loop: 25 k-steps ----
  for (int ks = 0; ks < 25; ++ks) {
    const int cur = ks & 1;
    if (ks < 24) stage_tile(Wh, Wl, tile[cur ^ 1], (ks + 1) * 32, tid);

    // A prefetch for ks+1 (masked past DD; zeros harmless, B zero-padded)
    float nf0[8] = {0,0,0,0,0,0,0,0};
    float nf1[8] = {0,0,0,0,0,0,0,0};
    {
      const int nkb = (ks + 1) * 32 + quad * 8;
      if (nkb < DD) {
        float4 v0 = *(const float4*)(xr0 + nkb);
        float4 v1 = *(const float4*)(xr0 + nkb + 4);
        nf0[0]=v0.x; nf0[1]=v0.y; nf0[2]=v0.z; nf0[3]=v0.w;
        nf0[4]=v1.x; nf0[5]=v1.y; nf0[6]=v1.z; nf0[7]=v1.w;
        float4 w0 = *(const float4*)(xr1 + nkb);
        float4 w1 = *(const float4*)(xr1 + nkb + 4);
        nf1[0]=w0.x; nf1[1]=w0.y; nf1[2]=w0.z; nf1[3]=w0.w;
        nf1[4]=w1.x; nf1[5]=w1.y; nf1[6]=w1.z; nf1[7]=w1.w;
      }
    }

    // B frags from LDS (swizzled slots)
    short8 bh[10], bl[10];
    const unsigned short* tb = tile[cur];
    #pragma unroll
    for (int nt = 0; nt < 10; ++nt) {
      const int ro = (nt * 16 + n16) * 64;              // ushort units (128 B/row)
      bh[nt] = *(const short8*)(tb + ro + ((quad ^ sw) << 3));
      bl[nt] = *(const short8*)(tb + ro + (((4 | quad) ^ sw) << 3));
    }

    short8 ah0, al0, ah1, al1;
    cvt_split8(fa0, ah0, al0);
    cvt_split8(fa1, ah1, al1);

    #pragma unroll
    for (int nt = 0; nt < 10; ++nt) {
      acc[0][nt] = __builtin_amdgcn_mfma_f32_16x16x32_bf16(ah0, bh[nt], acc[0][nt], 0, 0, 0);
      acc[1][nt] = __builtin_amdgcn_mfma_f32_16x16x32_bf16(ah1, bh[nt], acc[1][nt], 0, 0, 0);
      acc[0][nt] = __builtin_amdgcn_mfma_f32_16x16x32_bf16(ah0, bl[nt], acc[0][nt], 0, 0, 0);
      acc[1][nt] = __builtin_amdgcn_mfma_f32_16x16x32_bf16(ah1, bl[nt], acc[1][nt], 0, 0, 0);
      acc[0][nt] = __builtin_amdgcn_mfma_f32_16x16x32_bf16(al0, bh[nt], acc[0][nt], 0, 0, 0);
      acc[1][nt] = __builtin_amdgcn_mfma_f32_16x16x32_bf16(al1, bh[nt], acc[1][nt], 0, 0, 0);
    }

    #pragma unroll
    for (int j = 0; j < 8; ++j) { fa0[j] = nf0[j]; fa1[j] = nf1[j]; }

    __syncthreads();   // next buffer fully staged (all waves), reads done
  }

  // ---- epilogue: D row = quad*4 + reg, col = n16 ----
  #pragma unroll
  for (int ms = 0; ms < 2; ++ms)
    #pragma unroll
    for (int nt = 0; nt < 10; ++nt)
      #pragma unroll
      for (int r = 0; r < 4; ++r) {
        const int row = mbase + ms * 16 + quad * 4 + r;
        U[(size_t)row * NT + nt * 16 + n16] = acc[ms][nt][r];
      }
}

// ---------------------------------------------------------------------------
// Recurrent scan: REVERTED to v3 (known 82 us). v4/v5 register-residency
// fixes both failed (VGPR stayed 52-84; allocator spills G regardless) and
// regressed to 125/142 us. v3 structure: 512 blocks x 256 threads, one batch
// row per block, g[20][5] per thread, one LDS-only barrier per step,
// U prefetch 1 ahead, butterfly reduce over lane bits 3..5.
// ---------------------------------------------------------------------------
__global__ __launch_bounds__(256, 2) void recur_kernel(
    const float* __restrict__ ws,
    const float* __restrict__ be, const float* __restrict__ bi,
    float* __restrict__ out) {
  __shared__ float rbuf[2][NT];       // [parity][j]
  __shared__ float balbuf[2][NT];
  __shared__ float biasL[NT];

  const int tid  = threadIdx.x;
  const int lane = tid & 63;
  const int wave = tid >> 6;
  const int jc   = (wave << 3) | (lane & 7);  // 0..31
  const int kc   = (lane >> 3) & 7;           // 0..7
  const int j0   = jc * 5;
  const int k0   = kc * 20;
  const int b    = blockIdx.x;

  const float* G = ws + G_OFF;
  const float* U = ws + U_OFF;

  float g[20][5];
  #pragma unroll
  for (int kk = 0; kk < 20; ++kk)
    #pragma unroll
    for (int c = 0; c < 5; ++c)
      g[kk][c] = G[(size_t)(k0 + kk) * NT + j0 + c];

  if (tid < NT) biasL[tid] = (tid < NE) ? be[tid] : bi[tid - NE];
  for (int i = tid; i < 2 * NT; i += 256) (&rbuf[0][0])[i] = 0.f;

  const bool owner = (kc == 0);
  float u[5];
  if (owner) {
    const size_t ub = ((size_t)b * LL) * NT + j0;
    #pragma unroll
    for (int c = 0; c < 5; ++c) u[c] = U[ub + c];
  }
  float s[5];
  #pragma unroll
  for (int c = 0; c < 5; ++c) s[c] = 0.f;

  __syncthreads();

  for (int l = 0; l < LL; ++l) {
    const int p = l & 1;
    // ---- store step l-1 outputs (no barrier depends on these) ----
    if (l > 0) {
      const size_t ob = (size_t)b * LL + (l - 1);
      if (tid < NE) {
        out[O_RE   + ob * NE + tid] = rbuf[p][tid];
        out[O_BALE + ob * NE + tid] = balbuf[p][tid];
      } else if (tid < NT) {
        const int j2 = tid - NE;
        out[O_RI   + ob * NI + j2] = rbuf[p][NE + j2];
        out[O_BALI + ob * NI + j2] = balbuf[p][NE + j2];
      }
    }
    // ---- prefetch next step's U (owners) ----
    float nu[5];
    if (owner && l + 1 < LL) {
      const size_t nb = ((size_t)b * LL + (l + 1)) * NT + j0;
      #pragma unroll
      for (int c = 0; c < 5; ++c) nu[c] = U[nb + c];
    }
    // ---- partial dots over this thread's k-chunk ----
    float a[5];
    #pragma unroll
    for (int c = 0; c < 5; ++c) a[c] = 0.f;
    #pragma unroll
    for (int kk4 = 0; kk4 < 5; ++kk4) {
      float4 rv = *(const float4*)(&rbuf[p][k0 + kk4 * 4]);
      #pragma unroll
      for (int c = 0; c < 5; ++c)
        a[c] += rv.x * g[kk4*4+0][c] + rv.y * g[kk4*4+1][c]
              + rv.z * g[kk4*4+2][c] + rv.w * g[kk4*4+3][c];
    }
    // ---- butterfly reduce over kc (lane bits 3..5) ----
    #pragma unroll
    for (int c = 0; c < 5; ++c) {
      float v = a[c];
      v += __shfl_xor(v, 8, 64);
      v += __shfl_xor(v, 16, 64);
      v += __shfl_xor(v, 32, 64);
      a[c] = v;
    }
    // ---- owner lanes update state, write next-parity buffers ----
    if (owner) {
      #pragma unroll
      for (int c = 0; c < 5; ++c) {
        float bal = a[c] + u[c];
        balbuf[1 - p][j0 + c] = bal;
        float sn = 0.5f * (s[c] + bal + biasL[j0 + c]);
        s[c] = sn;
        rbuf[1 - p][j0 + c] = fmaxf(sn, 0.f);
      }
      #pragma unroll
      for (int c = 0; c < 5; ++c) u[c] = nu[c];
    }
    LDS_BARRIER();
  }
  // ---- final store: step 63 outputs live in parity-0 buffers ----
  {
    const size_t ob = (size_t)b * LL + 63;
    if (tid < NE) {
      out[O_RE   + ob * NE + tid] = rbuf[0][tid];
      out[O_BALE + ob * NE + tid] = balbuf[0][tid];
    } else if (tid < NT) {
      const int j2 = tid - NE;
      out[O_RI   + ob * NI + j2] = rbuf[0][NE + j2];
      out[O_BALI + ob * NI + j2] = balbuf[0][NE + j2];
    }
  }
}

// ---------------------------------------------------------------------------
// Logits v2 (MFMA): [32768 x 128] @ Wro^T (padded to 16 cols) + bro.
// Old version: thread-per-(m,c) scalar fp32 dots, 10 threads re-reading each
// 512 B re-row (10x read amplification, scalar FMA chain). New: one MFMA
// GEMM, split-bf16 3-pass (same precision path as the U GEMM, which passes).
// 256 blocks x 4 waves; wave computes 32 rows x 16 cols (cols 10..15 are
// zero-padded B). A: re rows fp32 from global, cvt in-reg. B: Wro staged
// once to LDS planes [16][136] (row pad breaks bank alignment).
// acc C-init = bro[col] handles the bias for free.
// D layout: row = quad*4 + r, col = lane&15.
// ---------------------------------------------------------------------------
__global__ __launch_bounds__(256) void logits_kernel(const float* __restrict__ Wro,
                                                     const float* __restrict__ bro,
                                                     float* __restrict__ out) {
  __shared__ unsigned short BH[16][136];
  __shared__ unsigned short BL[16][136];
  __shared__ float broL[16];

  const int tid  = threadIdx.x;
  const int lane = tid & 63;
  const int wave = tid >> 6;
  const int n16  = lane & 15;
  const int quad = lane >> 4;

  // stage + split Wro (rows 10..15 zero)
  for (int i = tid; i < 16 * NE; i += 256) {
    const int n = i >> 7, k = i & 127;
    float v = (n < NC) ? Wro[n * NE + k] : 0.f;
    unsigned short h = f2bf(v);
    BH[n][k] = h;
    BL[n][k] = f2bf(v - bf2f(h));
  }
  if (tid < 16) broL[tid] = (tid < NC) ? bro[tid] : 0.f;
  __syncthreads();

  const int mbase = blockIdx.x * 128 + wave * 32;
  const float* re = out + O_RE;

  af4 acc[2];
  #pragma unroll
  for (int ms = 0; ms < 2; ++ms)
    #pragma unroll
    for (int r = 0; r < 4; ++r) acc[ms][r] = broL[n16];

  // A: 2 m-subtiles x 4 k-frags of re rows (fp32 -> split bf16)
  short8 ah[2][4], al[2][4];
  #pragma unroll
  for (int ms = 0; ms < 2; ++ms) {
    const float* row = re + (size_t)(mbase + ms * 16 + n16) * NE;
    #pragma unroll
    for (int kf = 0; kf < 4; ++kf) {
      const int kb = kf * 32 + quad * 8;
      float4 v0 = *(const float4*)(row + kb);
      float4 v1 = *(const float4*)(row + kb + 4);
      float f[8] = {v0.x, v0.y, v0.z, v0.w, v1.x, v1.y, v1.z, v1.w};
      cvt_split8(f, ah[ms][kf], al[ms][kf]);
    }
  }
  // B frags from LDS
  short8 bh[4], bl[4];
  #pragma unroll
  for (int kf = 0; kf < 4; ++kf) {
    const int kb = kf * 32 + quad * 8;
    bh[kf] = *(const short8*)(&BH[n16][kb]);
    bl[kf] = *(const short8*)(&BL[n16][kb]);
  }
  #pragma unroll
  for (int kf = 0; kf < 4; ++kf)
    #pragma unroll
    for (int ms = 0; ms < 2; ++ms) {
      acc[ms] = __builtin_amdgcn_mfma_f32_16x16x32_bf16(ah[ms][kf], bh[kf], acc[ms], 0, 0, 0);
      acc[ms] = __builtin_amdgcn_mfma_f32_16x16x32_bf16(ah[ms][kf], bl[kf], acc[ms], 0, 0, 0);
      acc[ms] = __builtin_amdgcn_mfma_f32_16x16x32_bf16(al[ms][kf], bh[kf], acc[ms], 0, 0, 0);
    }

  if (n16 < NC) {
    #pragma unroll
    for (int ms = 0; ms < 2; ++ms)
      #pragma unroll
      for (int r = 0; r < 4; ++r) {
        const int m = mbase + ms * 16 + quad * 4 + r;
        out[O_LOGITS + (size_t)m * NC + n16] = acc[ms][r];
        if ((m & 63) == 63)
          out[O_LAST + (size_t)(m >> 6) * NC + n16] = acc[ms][r];
      }
  }
}

extern "C" void kernel_launch(void* const* d_in, const int* in_sizes, int n_in,
                              void* d_out, int out_size, void* d_ws, size_t ws_size,
                              hipStream_t stream) {
  const float* x   = (const float*)d_in[0];
  const float* Wxe = (const float*)d_in[1];
  const float* Wxi = (const float*)d_in[2];
  const float* Wee = (const float*)d_in[3];
  const float* Wie = (const float*)d_in[4];
  const float* Wei = (const float*)d_in[5];
  const float* Wii = (const float*)d_in[6];
  const float* be  = (const float*)d_in[7];
  const float* bi  = (const float*)d_in[8];
  const float* Wro = (const float*)d_in[9];
  const float* bro = (const float*)d_in[10];
  float* ws  = (float*)d_ws;
  float* out = (float*)d_out;

  hipLaunchKernelGGL(prep_kernel, dim3((G_SZ + NT*KP + 255)/256), dim3(256), 0, stream,
                     Wxe, Wxi, Wee, Wie, Wei, Wii, ws);
  hipLaunchKernelGGL(gemm_kernel, dim3(MM/128), dim3(256), 0, stream,
                     x, ws, ws + U_OFF);
  hipLaunchKernelGGL(recur_kernel, dim3(BB), dim3(256), 0, stream,
                     ws, be, bi, out);
  hipLaunchKernelGGL(logits_kernel, dim3(MM/128), dim3(256), 0, stream,
                     Wro, bro, out);
}